// Round 1
// baseline (439.531 us; speedup 1.0000x reference)
//
#include <hip/hip_runtime.h>

#define S 512
#define B 1024
#define K 48
#define LOG2E 1.4426950408889634f
#define LN2   0.6931471805599453f

__device__ __forceinline__ float rl(float v, int l) {
    return __int_as_float(__builtin_amdgcn_readlane(__float_as_int(v), l));
}

__global__ void __launch_bounds__(64) zero_out(float* o) {
    if (threadIdx.x == 0) o[0] = 0.f;
}

__global__ void __launch_bounds__(64) crf_kernel(
    const float* __restrict__ em, const int* __restrict__ tags,
    const int* __restrict__ mask, const float* __restrict__ trans,
    const float* __restrict__ start_tr, const float* __restrict__ end_tr,
    float* __restrict__ out)
{
    const int b    = blockIdx.x;   // one wave per batch element
    const int lane = threadIdx.x;

    // ---------------- score (lane-parallel over t) ----------------
    float sc = 0.f;
    int mcnt = 0;
    #pragma unroll
    for (int i = 0; i < S / 64; ++i) {
        int t   = lane + 64 * i;
        int tag = tags[t * B + b];
        int mk  = mask[t * B + b];
        mcnt += mk;
        if (t == 0) {
            sc += start_tr[tag] + em[(size_t)b * K + tag];
        } else {
            int tagp  = tags[(t - 1) * B + b];
            float add = trans[tagp * K + tag] + em[((size_t)t * B + b) * K + tag];
            sc += mk ? add : 0.f;
        }
    }
    #pragma unroll
    for (int off = 32; off > 0; off >>= 1) {
        sc   += __shfl_xor(sc, off);
        mcnt += __shfl_xor(mcnt, off);
    }
    int last_t = mcnt - 1;
    if (last_t < 0) last_t += S;          // mirrors python negative indexing
    sc += end_tr[tags[last_t * B + b]];

    // ---------------- partition (forward algorithm) ----------------
    const int  j      = (lane < K) ? lane : 0;   // inactive lanes mirror col 0, never read
    const bool active = lane < K;

    // eT[k] = exp(T[k][j]) : lane j holds column j of exp(transitions)
    float eT[K];
    #pragma unroll
    for (int k = 0; k < K; ++k)
        eT[k] = __expf(trans[k * K + j]);

    // beta in log2 units; normalize by lane 0, track offset (wave-uniform)
    float beta   = (start_tr[j] + em[(size_t)b * K + j]) * LOG2E;
    float r0     = rl(beta, 0);
    float gamma  = beta - r0;
    float offset = r0;

    // prefetch ring: 8 timesteps ahead (1 wave/SIMD -> must hide HBM in-wave)
    const int PF = 8;
    float em_n[PF];
    int   mk_n[PF];
    #pragma unroll
    for (int i = 0; i < PF; ++i) {
        int t   = 1 + i;
        em_n[i] = em[((size_t)t * B + b) * K + j];
        mk_n[i] = mask[t * B + b];
    }

    for (int t0 = 1; t0 < S; t0 += PF) {
        #pragma unroll
        for (int u = 0; u < PF; ++u) {
            int t = t0 + u;
            if (t >= S) break;
            float em_c = em_n[u];
            int   m_c  = mk_n[u];
            int   tp   = t + PF;
            if (tp < S) {
                em_n[u] = em[((size_t)tp * B + b) * K + j];
                mk_n[u] = mask[tp * B + b];
            }
            if (m_c) {  // wave-uniform branch (mask is per (t,b))
                float eg = exp2f(gamma);   // lane k's 2^gamma[k]
                float a0 = 0.f, a1 = 0.f, a2 = 0.f, a3 = 0.f;
                #pragma unroll
                for (int k = 0; k < K; k += 4) {
                    a0 = fmaf(rl(eg, k    ), eT[k    ], a0);
                    a1 = fmaf(rl(eg, k + 1), eT[k + 1], a1);
                    a2 = fmaf(rl(eg, k + 2), eT[k + 2], a2);
                    a3 = fmaf(rl(eg, k + 3), eT[k + 3], a3);
                }
                float s   = (a0 + a1) + (a2 + a3);
                float raw = __log2f(s) + em_c * LOG2E;
                float rr  = rl(raw, 0);
                gamma   = raw - rr;
                offset += rr;
            }
        }
    }

    // partition = ln2 * (offset + log2( sum_j 2^(gamma[j] + end[j]*log2e) ))
    float val = active ? exp2f(gamma + end_tr[j] * LOG2E) : 0.f;
    #pragma unroll
    for (int off = 32; off > 0; off >>= 1) val += __shfl_xor(val, off);
    float partition = (offset + __log2f(val)) * LN2;

    if (lane == 0) atomicAdd(out, partition - sc);
}

extern "C" void kernel_launch(void* const* d_in, const int* in_sizes, int n_in,
                              void* d_out, int out_size, void* d_ws, size_t ws_size,
                              hipStream_t stream) {
    const float* em       = (const float*)d_in[0];
    const int*   tags     = (const int*)d_in[1];
    const int*   mask     = (const int*)d_in[2];
    const float* trans    = (const float*)d_in[3];
    const float* start_tr = (const float*)d_in[4];
    const float* end_tr   = (const float*)d_in[5];
    float* out = (float*)d_out;

    zero_out<<<dim3(1), dim3(64), 0, stream>>>(out);
    crf_kernel<<<dim3(B), dim3(64), 0, stream>>>(em, tags, mask, trans,
                                                 start_tr, end_tr, out);
}

// Round 2
// 319.423 us; speedup vs baseline: 1.3760x; 1.3760x over previous
//
#include <hip/hip_runtime.h>

#define S 512
#define B 1024
#define K 48
#define LN2 0.6931471805599453f
#define PF 8

__global__ void __launch_bounds__(64) zero_out(float* o) {
    if (threadIdx.x == 0) o[0] = 0.f;
}

// s_j = sum_k aa[k] * eT[k]  (aa broadcast identical across lanes, eT per-lane column j)
__device__ __forceinline__ float matvec48(const float4* f, const float* eT) {
    float s0 = 0.f, s1 = 0.f, s2 = 0.f, s3 = 0.f;
    #pragma unroll
    for (int i = 0; i < 12; ++i) {
        s0 = fmaf(f[i].x, eT[4 * i + 0], s0);
        s1 = fmaf(f[i].y, eT[4 * i + 1], s1);
        s2 = fmaf(f[i].z, eT[4 * i + 2], s2);
        s3 = fmaf(f[i].w, eT[4 * i + 3], s3);
    }
    return (s0 + s1) + (s2 + s3);
}

__global__ void __launch_bounds__(64) crf_kernel(
    const float* __restrict__ em, const int* __restrict__ tags,
    const int* __restrict__ mask, const float* __restrict__ trans,
    const float* __restrict__ start_tr, const float* __restrict__ end_tr,
    float* __restrict__ out)
{
    const int b    = blockIdx.x;   // one wave per batch element
    const int lane = threadIdx.x;
    __shared__ __align__(16) float sh[K];

    // ---------------- score (lane-parallel over t) ----------------
    float sc = 0.f;
    int mcnt = 0;
    #pragma unroll
    for (int i = 0; i < S / 64; ++i) {
        int t   = lane + 64 * i;
        int tag = tags[t * B + b];
        int mk  = mask[t * B + b];
        mcnt += mk;
        if (t == 0) {
            sc += start_tr[tag] + em[(size_t)b * K + tag];
        } else {
            int tagp  = tags[(t - 1) * B + b];
            float add = trans[tagp * K + tag] + em[((size_t)t * B + b) * K + tag];
            sc += mk ? add : 0.f;
        }
    }
    #pragma unroll
    for (int off = 32; off > 0; off >>= 1) {
        sc   += __shfl_xor(sc, off);
        mcnt += __shfl_xor(mcnt, off);
    }
    int last_t = mcnt - 1;
    if (last_t < 0) last_t += S;
    sc += end_tr[tags[last_t * B + b]];

    // ---------------- partition: linear-space forward algorithm ----------------
    const int  j      = (lane < K) ? lane : 0;   // idle lanes mirror column 0
    const bool active = lane < K;

    // eT[k] = exp(T[k][j]); lane j holds column j (constant over t)
    float eT[K];
    #pragma unroll
    for (int k = 0; k < K; ++k)
        eT[k] = __expf(trans[k * K + j]);

    // linear alpha, renorm offset in log2 units (exact power-of-2 scaling)
    float a      = __expf(start_tr[j] + em[(size_t)b * K + j]);
    int   offset = 0;
    float scale  = 1.0f;

    if (active) sh[j] = a;
    const float4* shv = (const float4*)sh;
    float4 f[12];
    #pragma unroll
    for (int i = 0; i < 12; ++i) f[i] = shv[i];   // broadcast read (in-wave DS order)

    // prefetch ring: raw em (loads in flight) + mask; exp computed 1 step pre-use
    float em_raw[PF];
    int   mk_n[PF];
    #pragma unroll
    for (int i = 0; i < PF; ++i) {
        em_raw[i] = em[((size_t)(1 + i) * B + b) * K + j];
        mk_n[i]   = mask[(size_t)(1 + i) * B + b];
    }
    float eexp_cur = __expf(em_raw[0]);

#define STEP(u_, t_, PFON_)                                                     \
    do {                                                                        \
        float s_   = matvec48(f, eT);                                           \
        float an_  = s_ * eexp_cur;                                             \
        a = mk_n[u_] ? an_ : a;          /* mask: keep old alpha */             \
        a *= scale;                       /* uniform 2^-E (1.0 most steps) */   \
        if (lane < K) sh[lane] = a;                                             \
        _Pragma("unroll")                                                       \
        for (int i2_ = 0; i2_ < 12; ++i2_) f[i2_] = shv[i2_];                   \
        eexp_cur = __expf(em_raw[((u_) + 1) & 7]);  /* for next step */         \
        if (PFON_) {                                                            \
            int tp_ = (t_) + PF;                                                \
            if (tp_ < S) {                                                      \
                em_raw[u_] = em[((size_t)tp_ * B + b) * K + j];                 \
                mk_n[u_]   = mask[(size_t)tp_ * B + b];                         \
            }                                                                   \
        }                                                                       \
        if (((u_) & 3) == 3) {           /* renorm bookkeeping, SALU path */    \
            int bits_ = __builtin_amdgcn_readlane(__float_as_int(a), 0);        \
            int E_    = ((bits_ >> 23) & 255) - 127;                            \
            offset += E_;                                                       \
            scale = __int_as_float((127 - E_) << 23);                           \
        } else {                                                                \
            scale = 1.0f;                                                       \
        }                                                                       \
    } while (0)

    // main: t = 1 .. 504  (63 blocks of 8)
    for (int t0 = 1; t0 <= S - 2 * PF + 1; t0 += PF) {
        #pragma unroll
        for (int u = 0; u < PF; ++u) {
            STEP(u, t0 + u, true);
        }
    }
    // tail: t = 505 .. 511 (ring pre-loaded, no prefetch)
    #pragma unroll
    for (int u = 0; u < PF - 1; ++u) {
        STEP(u, (S - PF + 1) + u, false);
    }
#undef STEP

    // partition = offset*ln2 + ln( sum_j a_j * exp(end_j) )
    float val = active ? a * __expf(end_tr[j]) : 0.f;
    #pragma unroll
    for (int off = 32; off > 0; off >>= 1) val += __shfl_xor(val, off);
    float partition = (float)offset * LN2 + __logf(val);

    if (lane == 0) atomicAdd(out, partition - sc);
}

extern "C" void kernel_launch(void* const* d_in, const int* in_sizes, int n_in,
                              void* d_out, int out_size, void* d_ws, size_t ws_size,
                              hipStream_t stream) {
    const float* em       = (const float*)d_in[0];
    const int*   tags     = (const int*)d_in[1];
    const int*   mask     = (const int*)d_in[2];
    const float* trans    = (const float*)d_in[3];
    const float* start_tr = (const float*)d_in[4];
    const float* end_tr   = (const float*)d_in[5];
    float* out = (float*)d_out;

    zero_out<<<dim3(1), dim3(64), 0, stream>>>(out);
    crf_kernel<<<dim3(B), dim3(64), 0, stream>>>(em, tags, mask, trans,
                                                 start_tr, end_tr, out);
}